// Round 20
// baseline (131.979 us; speedup 1.0000x reference)
//
#include <hip/hip_runtime.h>
#include <math.h>

#define T_SEQ 2048
#define E 768
#define WIN 1024
#define KDIM 768
#define HS_SZ ((size_t)4096 * 768)
#define SCALE 0.21650635094610965f

typedef _Float16 f16x8 __attribute__((ext_vector_type(8)));
typedef _Float16 f16x4 __attribute__((ext_vector_type(4)));
typedef float f32x4 __attribute__((ext_vector_type(4)));
typedef __attribute__((address_space(3))) _Float16 lf16;

#define MFMA16(a, b, c) __builtin_amdgcn_mfma_f32_16x16x32_f16(a, b, c, 0, 0, 0)

__device__ __forceinline__ void dma16(const _Float16* g, lf16* l) {
    __builtin_amdgcn_global_load_lds(
        (const __attribute__((address_space(1))) void*)g,
        (__attribute__((address_space(3))) void*)l, 16, 0, 0);
}

// T1 XCD-aware chunked block swizzle: consecutive LOGICAL blocks (which share
// operand panels) land on the SAME XCD's L2. bid%8 = XCD (round-robin dispatch),
// chunk = gridDim/8. Bijective when gridDim % 8 == 0.
__device__ __forceinline__ int xcdswz(int bid, int chunk) {
    return (bid & 7) * chunk + (bid >> 3);
}

// ---------------- prep: f16 casts + rotary table ----------------
__device__ __forceinline__ void cast8(const float* __restrict__ src,
                                      _Float16* __restrict__ dst, int i) {
    float4 a = *(const float4*)&src[i];
    float4 b = *(const float4*)&src[i + 4];
    f16x8 h;
    h[0] = (_Float16)a.x; h[1] = (_Float16)a.y; h[2] = (_Float16)a.z; h[3] = (_Float16)a.w;
    h[4] = (_Float16)b.x; h[5] = (_Float16)b.y; h[6] = (_Float16)b.z; h[7] = (_Float16)b.w;
    *(f16x8*)&dst[i] = h;
}

__global__ __launch_bounds__(256) void prep(
    const float* __restrict__ hs,
    const float* __restrict__ Wq, const float* __restrict__ Wk,
    const float* __restrict__ Wv, const float* __restrict__ Wo,
    _Float16* __restrict__ hs16,
    _Float16* __restrict__ Wq16, _Float16* __restrict__ Wk16,
    _Float16* __restrict__ Wv16, _Float16* __restrict__ Wo16,
    float2* __restrict__ rtab) {
    int tid = blockIdx.x * 256 + threadIdx.x;
    int i = tid * 8;
    if (i < 768 * 768) { cast8(Wq, Wq16, i); cast8(Wo, Wo16, i); }
    if (i < 192 * 768) { cast8(Wk, Wk16, i); cast8(Wv, Wv16, i); }
    cast8(hs, hs16, i);
    if (tid < 2048 * 32) {
        int t = tid >> 5, d = tid & 31;
        float inv = powf(10000.0f, -(float)(2 * d) * (1.0f / 64.0f));
        float s, c;
        sincosf((float)t * inv, &s, &c);
        rtab[tid] = make_float2(c, s);
    }
}

// ---------------- QKV GEMM: pure f16, 128x64, BK=128, DMA + XOR swizzle -----
// grid = 576 (1D); logical (bx, m0) decoded after XCD swizzle so that all 18
// bx blocks sharing one A-slice live on one XCD's L2.
__global__ __launch_bounds__(256) void gemm_qkv(
    const _Float16* __restrict__ A16,
    const _Float16* __restrict__ Wq16, const _Float16* __restrict__ Wk16,
    const _Float16* __restrict__ Wv16, const float2* __restrict__ rtab,
    _Float16* __restrict__ q16, _Float16* __restrict__ k16,
    _Float16* __restrict__ vT16) {
    __shared__ __align__(16) _Float16 As[128 * 128];   // 32 KB, swizzled
    __shared__ __align__(16) _Float16 Bs[64 * 128];    // 16 KB, swizzled
    const int tid = threadIdx.x;
    const int lb = xcdswz(blockIdx.x, 72);             // 576/8
    const int bx = lb % 18;
    const int m0 = (lb / 18) * 128;
    const int w = tid >> 6, lane = tid & 63;
    const int mm = lane & 15, quad = lane >> 4;

    const _Float16* bbase; int brb;
    if (bx < 12)      { bbase = Wq16; brb = bx * 64; }
    else if (bx < 15) { bbase = Wk16; brb = (bx - 12) * 64; }
    else              { bbase = Wv16; brb = (bx - 15) * 64; }

    const int rofs4 = lane >> 4;
    const int gs = lane & 15;

    const _Float16* agp[8]; lf16* alp[8];
    #pragma unroll
    for (int j = 0; j < 8; ++j) {
        int c = j * 4 + w;
        int rr = c * 4 + rofs4;
        int glog = gs ^ (rr & 15);
        agp[j] = A16 + (size_t)(m0 + rr) * KDIM + glog * 8;
        alp[j] = ((lf16*)As) + c * 512 + lane * 8;
    }
    const _Float16* bgp[4]; lf16* blp[4];
    #pragma unroll
    for (int j = 0; j < 4; ++j) {
        int c = j * 4 + w;
        int rr = c * 4 + rofs4;
        int glog = gs ^ (rr & 15);
        bgp[j] = bbase + (size_t)(brb + rr) * KDIM + glog * 8;
        blp[j] = ((lf16*)Bs) + c * 512 + lane * 8;
    }

    f32x4 acc[2][4] = {};

    for (int it = 0; it < 6; ++it) {
        const int ke = it * 128;
        __syncthreads();
        #pragma unroll
        for (int j = 0; j < 8; ++j) dma16(agp[j] + ke, alp[j]);
        #pragma unroll
        for (int j = 0; j < 4; ++j) dma16(bgp[j] + ke, blp[j]);
        __syncthreads();
        #pragma unroll
        for (int s = 0; s < 4; ++s) {
            const int gq = ((s * 4 + quad) ^ mm) * 8;
            f16x8 ah[2];
            #pragma unroll
            for (int mt = 0; mt < 2; ++mt)
                ah[mt] = *(const f16x8*)&As[(w * 32 + mt * 16 + mm) * 128 + gq];
            #pragma unroll
            for (int nt = 0; nt < 4; ++nt) {
                f16x8 bh = *(const f16x8*)&Bs[(nt * 16 + mm) * 128 + gq];
                #pragma unroll
                for (int mt = 0; mt < 2; ++mt)
                    acc[mt][nt] = MFMA16(ah[mt], bh, acc[mt][nt]);
            }
        }
    }

    // ---- fused epilogue ----
    if (bx < 12) {
        // Q: rotary + scale, f16 emit
        #pragma unroll
        for (int mt = 0; mt < 2; ++mt)
            #pragma unroll
            for (int r = 0; r < 4; ++r) {
                int row = m0 + w * 32 + mt * 16 + quad * 4 + r;
                int t = row & (T_SEQ - 1);
                _Float16* dst = &q16[(size_t)row * E + bx * 64 + mm];
                #pragma unroll
                for (int nt = 0; nt < 2; ++nt) {
                    int d = nt * 16 + mm;
                    float2 cs = rtab[t * 32 + d];
                    float x1 = acc[mt][nt][r], x2 = acc[mt][nt + 2][r];
                    dst[nt * 16]       = (_Float16)((x1 * cs.x - x2 * cs.y) * SCALE);
                    dst[(nt + 2) * 16] = (_Float16)((x1 * cs.y + x2 * cs.x) * SCALE);
                }
            }
    } else if (bx < 15) {
        // K: rotary, f16 emit
        int kvh = bx - 12;
        #pragma unroll
        for (int mt = 0; mt < 2; ++mt)
            #pragma unroll
            for (int r = 0; r < 4; ++r) {
                int row = m0 + w * 32 + mt * 16 + quad * 4 + r;
                int t = row & (T_SEQ - 1);
                int b = row >> 11;
                _Float16* dst = &k16[(((size_t)(b * 3 + kvh)) * T_SEQ + t) * 64 + mm];
                #pragma unroll
                for (int nt = 0; nt < 2; ++nt) {
                    int d = nt * 16 + mm;
                    float2 cs = rtab[t * 32 + d];
                    float x1 = acc[mt][nt][r], x2 = acc[mt][nt + 2][r];
                    dst[nt * 16]       = (_Float16)(x1 * cs.x - x2 * cs.y);
                    dst[(nt + 2) * 16] = (_Float16)(x1 * cs.y + x2 * cs.x);
                }
            }
    } else {
        // V: transpose through LDS (As is free), coalesced f16x8 rows.
        __syncthreads();                               // K-loop LDS reads done
        _Float16 (*vs)[136] = (_Float16 (*)[136])As;   // [64 d][128 t + pad 8]
        #pragma unroll
        for (int mt = 0; mt < 2; ++mt)
            #pragma unroll
            for (int nt = 0; nt < 4; ++nt) {
                f16x4 pv;
                #pragma unroll
                for (int r = 0; r < 4; ++r) pv[r] = (_Float16)acc[mt][nt][r];
                *(f16x4*)&vs[nt * 16 + mm][w * 32 + mt * 16 + quad * 4] = pv;
            }
        __syncthreads();
        const int kvh = bx - 15;
        const int b = m0 >> 11, tbase = m0 & (T_SEQ - 1);
        const int tl = (tid & 15) * 8;                 // 16 lanes cover 128 t contiguous
        #pragma unroll
        for (int j = 0; j < 4; ++j) {
            int dd = (tid >> 4) + j * 16;
            f16x8 vv = *(const f16x8*)&vs[dd][tl];
            *(f16x8*)&vT16[(((size_t)(b * 3 + kvh)) * 64 + dd) * T_SEQ + tbase + tl] = vv;
        }
    }
}

// ---------------- output-projection GEMM: 128x128 tile, BK=128, DMA+swizzle -
// grid = 192 (1D); N=128 halves A-panel staging (6 col-blocks/panel vs 12).
__global__ __launch_bounds__(256) void gemm_out(
    const _Float16* __restrict__ A16, const _Float16* __restrict__ B16,
    float* __restrict__ C) {
    __shared__ __align__(16) _Float16 As[128 * 128];   // 32 KB
    __shared__ __align__(16) _Float16 Bs[128 * 128];   // 32 KB
    const int tid = threadIdx.x;
    const int lb = xcdswz(blockIdx.x, 24);             // 192/8
    const int n0 = (lb % 6) * 128;
    const int m0 = (lb / 6) * 128;
    const int w = tid >> 6, lane = tid & 63;
    const int mm = lane & 15, quad = lane >> 4;

    const int rofs4 = lane >> 4;
    const int gs = lane & 15;

    const _Float16* agp[8]; lf16* alp[8];
    #pragma unroll
    for (int j = 0; j < 8; ++j) {
        int c = j * 4 + w;
        int rr = c * 4 + rofs4;
        int glog = gs ^ (rr & 15);
        agp[j] = A16 + (size_t)(m0 + rr) * KDIM + glog * 8;
        alp[j] = ((lf16*)As) + c * 512 + lane * 8;
    }
    const _Float16* bgp[8]; lf16* blp[8];
    #pragma unroll
    for (int j = 0; j < 8; ++j) {
        int c = j * 4 + w;
        int rr = c * 4 + rofs4;
        int glog = gs ^ (rr & 15);
        bgp[j] = B16 + (size_t)(n0 + rr) * KDIM + glog * 8;
        blp[j] = ((lf16*)Bs) + c * 512 + lane * 8;
    }

    f32x4 acc[2][8] = {};

    for (int it = 0; it < 6; ++it) {
        const int ke = it * 128;
        __syncthreads();
        #pragma unroll
        for (int j = 0; j < 8; ++j) dma16(agp[j] + ke, alp[j]);
        #pragma unroll
        for (int j = 0; j < 8; ++j) dma16(bgp[j] + ke, blp[j]);
        __syncthreads();
        #pragma unroll
        for (int s = 0; s < 4; ++s) {
            const int gq = ((s * 4 + quad) ^ mm) * 8;
            f16x8 ah[2];
            #pragma unroll
            for (int mt = 0; mt < 2; ++mt)
                ah[mt] = *(const f16x8*)&As[(w * 32 + mt * 16 + mm) * 128 + gq];
            #pragma unroll
            for (int nt = 0; nt < 8; ++nt) {
                f16x8 bh = *(const f16x8*)&Bs[(nt * 16 + mm) * 128 + gq];
                #pragma unroll
                for (int mt = 0; mt < 2; ++mt)
                    acc[mt][nt] = MFMA16(ah[mt], bh, acc[mt][nt]);
            }
        }
    }

    #pragma unroll
    for (int mt = 0; mt < 2; ++mt)
        #pragma unroll
        for (int r = 0; r < 4; ++r) {
            int row = m0 + w * 32 + mt * 16 + quad * 4 + r;
            float* cp = &C[(size_t)row * 768 + n0 + mm];
            #pragma unroll
            for (int nt = 0; nt < 8; ++nt)
                cp[nt * 16] = acc[mt][nt][r];
        }
}

// ---------------- MFMA flash attention v6: dbuf LDS, 1 barrier/chunk -------
// grid = 768 (1D); 96 consecutive logical blocks (≈ one KV plane) per XCD.
__global__ __launch_bounds__(256) void attn_mfma(const _Float16* __restrict__ q16,
                                                 const _Float16* __restrict__ k16,
                                                 const _Float16* __restrict__ vT16,
                                                 _Float16* __restrict__ aout16) {
    __shared__ __align__(16) char smem[32768 + 10240];         // 42 KB
    _Float16* k_s  = (_Float16*)smem;                          // [2][64*64] swz
    _Float16* vT_s = (_Float16*)(smem + 16384);                // [2][64*64] swz
    _Float16 (*p_s)[40] = (_Float16(*)[40])(smem + 32768);     // [128][40]
    float* ored = (float*)smem;                                // [64][64] end overlay
    float* lred = (float*)(smem + 16384);                      // [64]     end overlay

    const int lb = xcdswz(blockIdx.x, 96);                     // 768/8
    const int b = lb / 384;
    const int rrem = lb % 384;
    const int h = rrem >> 5;
    const int i0 = (rrem & 31) * 64;
    const int plane = b * 3 + (h >> 2);
    const int tid = threadIdx.x;
    const int w = tid >> 6, lane = tid & 63;
    const int m = lane & 15, quad = lane >> 4;
    const int qh = w & 1, kh = w >> 1;
    const int xm = m & 7;

    int s0 = i0 - 512;      s0 = s0 < 0 ? 0 : (s0 > 1024 ? 1024 : s0);
    int sL = i0 + 63 - 512; sL = sL < 0 ? 0 : (sL > 1024 ? 1024 : sL);
    const int nc = (sL + WIN - s0 + 63) >> 6;

    int start_q[2];
    f16x8 qf[2][2];
    #pragma unroll
    for (int qt = 0; qt < 2; ++qt) {
        int qi = i0 + qh * 32 + qt * 16 + m;
        int sq = qi - 512; sq = sq < 0 ? 0 : (sq > 1024 ? 1024 : sq);
        start_q[qt] = sq;
        const _Float16* qp = &q16[((size_t)(b * T_SEQ + qi)) * E + h * 64 + quad * 8];
        qf[qt][0] = *(const f16x8*)&qp[0];
        qf[qt][1] = *(const f16x8*)&qp[32];
    }

    f32x4 o[2][4] = {};
    float l_run[2] = {0.0f, 0.0f};

    const int rofs = lane >> 3;
    const int glog = (lane & 7) ^ rofs;
    const _Float16* kgb[2]; const _Float16* vgb[2];
    _Float16* klw[2]; _Float16* vlw[2];
    #pragma unroll
    for (int j = 0; j < 2; ++j) {
        int rr = (j * 4 + w) * 8 + rofs;
        kgb[j] = k16 + ((size_t)plane * T_SEQ + rr) * 64 + glog * 8;
        vgb[j] = vT16 + ((size_t)plane * 64 + rr) * T_SEQ + glog * 8;
        klw[j] = k_s + (j * 4 + w) * 512 + lane * 8;
        vlw[j] = vT_s + (j * 4 + w) * 512 + lane * 8;
    }

    // prologue: chunk 0 -> regs -> buf0
    f16x8 kr[2], vr[2];
    #pragma unroll
    for (int j = 0; j < 2; ++j) {
        kr[j] = *(const f16x8*)(kgb[j] + (size_t)s0 * 64);
        vr[j] = *(const f16x8*)(vgb[j] + s0);
    }
    #pragma unroll
    for (int j = 0; j < 2; ++j) {
        *(f16x8*)klw[j] = kr[j];
        *(f16x8*)vlw[j] = vr[j];
    }

    for (int ci = 0; ci < nc; ++ci) {
        const int c0 = s0 + ci * 64;
        const int sel = (ci & 1) * 4096;
        __syncthreads();                 // buf[sel] visible; prev readers done
        if (ci + 1 < nc) {               // prefetch next chunk into regs
            const int cn = c0 + 64;
            #pragma unroll
            for (int j = 0; j < 2; ++j) {
                kr[j] = *(const f16x8*)(kgb[j] + (size_t)cn * 64);
                vr[j] = *(const f16x8*)(vgb[j] + cn);
            }
        }

        f32x4 st[2][2] = {};
        #pragma unroll
        for (int s = 0; s < 2; ++s) {
            #pragma unroll
            for (int kt = 0; kt < 2; ++kt) {
                int row = kh * 32 + kt * 16 + m;
                int g = (s * 4 + quad) ^ xm;
                f16x8 a = *(const f16x8*)&k_s[sel + row * 64 + g * 8];
                #pragma unroll
                for (int qt = 0; qt < 2; ++qt)
                    st[kt][qt] = MFMA16(a, qf[qt][s], st[kt][qt]);
            }
        }

        const bool boundary = (c0 < sL) || (c0 + 63 > s0 + 1023);
        if (boundary) {
            #pragma unroll
            for (int kt = 0; kt < 2; ++kt)
                #pragma unroll
                for (int qt = 0; qt < 2; ++qt)
                    #pragma unroll
                    for (int r = 0; r < 4; ++r) {
                        int j = c0 + kh * 32 + kt * 16 + quad * 4 + r;
                        bool valid = (j >= start_q[qt]) && (j < start_q[qt] + WIN);
                        st[kt][qt][r] = valid ? st[kt][qt][r] : -INFINITY;
                    }
        }

        #pragma unroll
        for (int kt = 0; kt < 2; ++kt)
            #pragma unroll
            for (int qt = 0; qt < 2; ++qt) {
                float p0 = __expf(st[kt][qt][0]);
                float p1 = __expf(st[kt][qt][1]);
                float p2 = __expf(st[kt][qt][2]);
                float p3 = __expf(st[kt][qt][3]);
                l_run[qt] += (p0 + p1) + (p2 + p3);
                f16x4 pv = {(_Float16)p0, (_Float16)p1, (_Float16)p2, (_Float16)p3};
                *(f16x4*)&p_s[w * 32 + qt * 16 + m][kt * 16 + quad * 4] = pv;
            }

        f16x8 bp[2];
        #pragma unroll
        for (int qt = 0; qt < 2; ++qt)
            bp[qt] = *(const f16x8*)&p_s[w * 32 + qt * 16 + m][quad * 8];
        #pragma unroll
        for (int mt = 0; mt < 4; ++mt) {
            int g = (kh * 4 + quad) ^ xm;
            f16x8 a = *(const f16x8*)&vT_s[sel + (mt * 16 + m) * 64 + g * 8];
            #pragma unroll
            for (int qt = 0; qt < 2; ++qt)
                o[qt][mt] = MFMA16(a, bp[qt], o[qt][mt]);
        }

        if (ci + 1 < nc) {               // write next chunk to other buffer
            const int ns = ((ci + 1) & 1) * 4096;
            #pragma unroll
            for (int j = 0; j < 2; ++j) {
                *(f16x8*)(klw[j] + ns) = kr[j];
                *(f16x8*)(vlw[j] + ns) = vr[j];
            }
        }
    }

    float l_tot[2];
    #pragma unroll
    for (int qt = 0; qt < 2; ++qt) {
        float l = l_run[qt];
        l += __shfl_xor(l, 16);
        l += __shfl_xor(l, 32);
        l_tot[qt] = l;
    }

    __syncthreads();
    if (kh == 1) {
        #pragma unroll
        for (int qt = 0; qt < 2; ++qt) {
            #pragma unroll
            for (int mt = 0; mt < 4; ++mt) {
                int idx = ((qh * 32 + qt * 16 + m) << 6) + mt * 16 + quad * 4;
                *(float4*)&ored[idx] = *(float4*)&o[qt][mt];
            }
            if (quad == 0) lred[qh * 32 + qt * 16 + m] = l_tot[qt];
        }
    }
    __syncthreads();
    if (kh == 0) {
        #pragma unroll
        for (int qt = 0; qt < 2; ++qt) {
            float rl = 1.0f / (l_tot[qt] + lred[qh * 32 + qt * 16 + m]);
            int qi = i0 + qh * 32 + qt * 16 + m;
            _Float16* op = &aout16[((size_t)(b * T_SEQ + qi)) * E + h * 64];
            #pragma unroll
            for (int mt = 0; mt < 4; ++mt) {
                int idx = ((qh * 32 + qt * 16 + m) << 6) + mt * 16 + quad * 4;
                float4 other = *(float4*)&ored[idx];
                f16x4 hv;
                #pragma unroll
                for (int r = 0; r < 4; ++r)
                    hv[r] = (_Float16)((o[qt][mt][r] + (&other.x)[r]) * rl);
                *(f16x4*)&op[mt * 16 + quad * 4] = hv;
            }
        }
    }
}

extern "C" void kernel_launch(void* const* d_in, const int* in_sizes, int n_in,
                              void* d_out, int out_size, void* d_ws, size_t ws_size,
                              hipStream_t stream) {
    const float* hs = (const float*)d_in[0];
    const float* Wq = (const float*)d_in[1];
    const float* Wk = (const float*)d_in[2];
    const float* Wv = (const float*)d_in[3];
    const float* Wo = (const float*)d_in[4];
    float* out = (float*)d_out;

    _Float16* hs16   = (_Float16*)d_ws;             // 4096*768 f16
    _Float16* aout16 = hs16 + HS_SZ;                // 4096*768
    _Float16* q16    = aout16 + HS_SZ;              // 4096*768
    _Float16* k16    = q16 + HS_SZ;                 // 6*2048*64
    _Float16* vT16   = k16 + 6 * 2048 * 64;         // 6*64*2048
    _Float16* Wq16   = vT16 + 6 * 2048 * 64;        // 768*768
    _Float16* Wk16   = Wq16 + 768 * 768;            // 192*768
    _Float16* Wv16   = Wk16 + 192 * 768;            // 192*768
    _Float16* Wo16   = Wv16 + 192 * 768;            // 768*768
    float2*   rtab   = (float2*)(Wo16 + 768 * 768); // 2048*32 float2

    dim3 blk(256);
    prep<<<dim3((int)(HS_SZ / 8 / 256)), blk, 0, stream>>>(hs, Wq, Wk, Wv, Wo,
                                                           hs16, Wq16, Wk16, Wv16, Wo16, rtab);
    gemm_qkv<<<dim3(576), blk, 0, stream>>>(hs16, Wq16, Wk16, Wv16, rtab, q16, k16, vT16);
    attn_mfma<<<dim3(768), blk, 0, stream>>>(q16, k16, vT16, aout16);
    gemm_out<<<dim3(192), blk, 0, stream>>>(aout16, Wo16, out);
}

// Round 22
// 128.454 us; speedup vs baseline: 1.0274x; 1.0274x over previous
//
#include <hip/hip_runtime.h>
#include <math.h>

#define T_SEQ 2048
#define E 768
#define WIN 1024
#define KDIM 768
#define HS_SZ ((size_t)4096 * 768)
#define SCALE 0.21650635094610965f

typedef _Float16 f16x8 __attribute__((ext_vector_type(8)));
typedef _Float16 f16x4 __attribute__((ext_vector_type(4)));
typedef float f32x4 __attribute__((ext_vector_type(4)));
typedef __attribute__((address_space(3))) _Float16 lf16;

#define MFMA16(a, b, c) __builtin_amdgcn_mfma_f32_16x16x32_f16(a, b, c, 0, 0, 0)

__device__ __forceinline__ void dma16(const _Float16* g, lf16* l) {
    __builtin_amdgcn_global_load_lds(
        (const __attribute__((address_space(1))) void*)g,
        (__attribute__((address_space(3))) void*)l, 16, 0, 0);
}

// T1 XCD-aware chunked block swizzle: consecutive LOGICAL blocks (which share
// operand panels) land on the SAME XCD's L2. bid%8 = XCD (round-robin dispatch),
// chunk = gridDim/8. Bijective when gridDim % 8 == 0.
// Measured: R18 127.7us vs R1 133.2us baseline (-4.1%).
__device__ __forceinline__ int xcdswz(int bid, int chunk) {
    return (bid & 7) * chunk + (bid >> 3);
}

// ---------------- prep: f16 casts + rotary table ----------------
__device__ __forceinline__ void cast8(const float* __restrict__ src,
                                      _Float16* __restrict__ dst, int i) {
    float4 a = *(const float4*)&src[i];
    float4 b = *(const float4*)&src[i + 4];
    f16x8 h;
    h[0] = (_Float16)a.x; h[1] = (_Float16)a.y; h[2] = (_Float16)a.z; h[3] = (_Float16)a.w;
    h[4] = (_Float16)b.x; h[5] = (_Float16)b.y; h[6] = (_Float16)b.z; h[7] = (_Float16)b.w;
    *(f16x8*)&dst[i] = h;
}

__global__ __launch_bounds__(256) void prep(
    const float* __restrict__ hs,
    const float* __restrict__ Wq, const float* __restrict__ Wk,
    const float* __restrict__ Wv, const float* __restrict__ Wo,
    _Float16* __restrict__ hs16,
    _Float16* __restrict__ Wq16, _Float16* __restrict__ Wk16,
    _Float16* __restrict__ Wv16, _Float16* __restrict__ Wo16,
    float2* __restrict__ rtab) {
    int tid = blockIdx.x * 256 + threadIdx.x;
    int i = tid * 8;
    if (i < 768 * 768) { cast8(Wq, Wq16, i); cast8(Wo, Wo16, i); }
    if (i < 192 * 768) { cast8(Wk, Wk16, i); cast8(Wv, Wv16, i); }
    cast8(hs, hs16, i);
    if (tid < 2048 * 32) {
        int t = tid >> 5, d = tid & 31;
        float inv = powf(10000.0f, -(float)(2 * d) * (1.0f / 64.0f));
        float s, c;
        sincosf((float)t * inv, &s, &c);
        rtab[tid] = make_float2(c, s);
    }
}

// ---------------- QKV GEMM: pure f16, 128x64, BK=128, DMA + XOR swizzle -----
// grid = 576 (1D); logical (bx, m0) decoded after XCD swizzle so that all 18
// bx blocks sharing one A-slice live on one XCD's L2.
__global__ __launch_bounds__(256) void gemm_qkv(
    const _Float16* __restrict__ A16,
    const _Float16* __restrict__ Wq16, const _Float16* __restrict__ Wk16,
    const _Float16* __restrict__ Wv16, const float2* __restrict__ rtab,
    _Float16* __restrict__ q16, _Float16* __restrict__ k16,
    _Float16* __restrict__ vT16) {
    __shared__ __align__(16) _Float16 As[128 * 128];   // 32 KB, swizzled
    __shared__ __align__(16) _Float16 Bs[64 * 128];    // 16 KB, swizzled
    const int tid = threadIdx.x;
    const int lb = xcdswz(blockIdx.x, 72);             // 576/8
    const int bx = lb % 18;
    const int m0 = (lb / 18) * 128;
    const int w = tid >> 6, lane = tid & 63;
    const int mm = lane & 15, quad = lane >> 4;

    const _Float16* bbase; int brb;
    if (bx < 12)      { bbase = Wq16; brb = bx * 64; }
    else if (bx < 15) { bbase = Wk16; brb = (bx - 12) * 64; }
    else              { bbase = Wv16; brb = (bx - 15) * 64; }

    const int rofs4 = lane >> 4;
    const int gs = lane & 15;

    const _Float16* agp[8]; lf16* alp[8];
    #pragma unroll
    for (int j = 0; j < 8; ++j) {
        int c = j * 4 + w;
        int rr = c * 4 + rofs4;
        int glog = gs ^ (rr & 15);
        agp[j] = A16 + (size_t)(m0 + rr) * KDIM + glog * 8;
        alp[j] = ((lf16*)As) + c * 512 + lane * 8;
    }
    const _Float16* bgp[4]; lf16* blp[4];
    #pragma unroll
    for (int j = 0; j < 4; ++j) {
        int c = j * 4 + w;
        int rr = c * 4 + rofs4;
        int glog = gs ^ (rr & 15);
        bgp[j] = bbase + (size_t)(brb + rr) * KDIM + glog * 8;
        blp[j] = ((lf16*)Bs) + c * 512 + lane * 8;
    }

    f32x4 acc[2][4] = {};

    for (int it = 0; it < 6; ++it) {
        const int ke = it * 128;
        __syncthreads();
        #pragma unroll
        for (int j = 0; j < 8; ++j) dma16(agp[j] + ke, alp[j]);
        #pragma unroll
        for (int j = 0; j < 4; ++j) dma16(bgp[j] + ke, blp[j]);
        __syncthreads();
        #pragma unroll
        for (int s = 0; s < 4; ++s) {
            const int gq = ((s * 4 + quad) ^ mm) * 8;
            f16x8 ah[2];
            #pragma unroll
            for (int mt = 0; mt < 2; ++mt)
                ah[mt] = *(const f16x8*)&As[(w * 32 + mt * 16 + mm) * 128 + gq];
            #pragma unroll
            for (int nt = 0; nt < 4; ++nt) {
                f16x8 bh = *(const f16x8*)&Bs[(nt * 16 + mm) * 128 + gq];
                #pragma unroll
                for (int mt = 0; mt < 2; ++mt)
                    acc[mt][nt] = MFMA16(ah[mt], bh, acc[mt][nt]);
            }
        }
    }

    // ---- fused epilogue ----
    if (bx < 12) {
        // Q: rotary + scale, f16 emit
        #pragma unroll
        for (int mt = 0; mt < 2; ++mt)
            #pragma unroll
            for (int r = 0; r < 4; ++r) {
                int row = m0 + w * 32 + mt * 16 + quad * 4 + r;
                int t = row & (T_SEQ - 1);
                _Float16* dst = &q16[(size_t)row * E + bx * 64 + mm];
                #pragma unroll
                for (int nt = 0; nt < 2; ++nt) {
                    int d = nt * 16 + mm;
                    float2 cs = rtab[t * 32 + d];
                    float x1 = acc[mt][nt][r], x2 = acc[mt][nt + 2][r];
                    dst[nt * 16]       = (_Float16)((x1 * cs.x - x2 * cs.y) * SCALE);
                    dst[(nt + 2) * 16] = (_Float16)((x1 * cs.y + x2 * cs.x) * SCALE);
                }
            }
    } else if (bx < 15) {
        // K: rotary, f16 emit
        int kvh = bx - 12;
        #pragma unroll
        for (int mt = 0; mt < 2; ++mt)
            #pragma unroll
            for (int r = 0; r < 4; ++r) {
                int row = m0 + w * 32 + mt * 16 + quad * 4 + r;
                int t = row & (T_SEQ - 1);
                int b = row >> 11;
                _Float16* dst = &k16[(((size_t)(b * 3 + kvh)) * T_SEQ + t) * 64 + mm];
                #pragma unroll
                for (int nt = 0; nt < 2; ++nt) {
                    int d = nt * 16 + mm;
                    float2 cs = rtab[t * 32 + d];
                    float x1 = acc[mt][nt][r], x2 = acc[mt][nt + 2][r];
                    dst[nt * 16]       = (_Float16)(x1 * cs.x - x2 * cs.y);
                    dst[(nt + 2) * 16] = (_Float16)(x1 * cs.y + x2 * cs.x);
                }
            }
    } else {
        // V: transpose through LDS (As is free), coalesced f16x8 rows.
        __syncthreads();                               // K-loop LDS reads done
        _Float16 (*vs)[136] = (_Float16 (*)[136])As;   // [64 d][128 t + pad 8]
        #pragma unroll
        for (int mt = 0; mt < 2; ++mt)
            #pragma unroll
            for (int nt = 0; nt < 4; ++nt) {
                f16x4 pv;
                #pragma unroll
                for (int r = 0; r < 4; ++r) pv[r] = (_Float16)acc[mt][nt][r];
                *(f16x4*)&vs[nt * 16 + mm][w * 32 + mt * 16 + quad * 4] = pv;
            }
        __syncthreads();
        const int kvh = bx - 15;
        const int b = m0 >> 11, tbase = m0 & (T_SEQ - 1);
        const int tl = (tid & 15) * 8;                 // 16 lanes cover 128 t contiguous
        #pragma unroll
        for (int j = 0; j < 4; ++j) {
            int dd = (tid >> 4) + j * 16;
            f16x8 vv = *(const f16x8*)&vs[dd][tl];
            *(f16x8*)&vT16[(((size_t)(b * 3 + kvh)) * 64 + dd) * T_SEQ + tbase + tl] = vv;
        }
    }
}

// ---------------- output-projection GEMM: 128x64 tile, BK=128, DMA+swizzle --
// grid = 384 (1D); 12 n0-blocks sharing an A-slice co-located per XCD.
// (N=64 measured best: R18 127.7 vs R20 N=128 132.0 — parallelism beats
//  per-block staging efficiency at this problem size.)
__global__ __launch_bounds__(256) void gemm_out(
    const _Float16* __restrict__ A16, const _Float16* __restrict__ B16,
    float* __restrict__ C) {
    __shared__ __align__(16) _Float16 As[128 * 128];   // 32 KB
    __shared__ __align__(16) _Float16 Bs[64 * 128];    // 16 KB
    const int tid = threadIdx.x;
    const int lb = xcdswz(blockIdx.x, 48);             // 384/8
    const int n0 = (lb % 12) * 64;
    const int m0 = (lb / 12) * 128;
    const int w = tid >> 6, lane = tid & 63;
    const int mm = lane & 15, quad = lane >> 4;

    const int rofs4 = lane >> 4;
    const int gs = lane & 15;

    const _Float16* agp[8]; lf16* alp[8];
    #pragma unroll
    for (int j = 0; j < 8; ++j) {
        int c = j * 4 + w;
        int rr = c * 4 + rofs4;
        int glog = gs ^ (rr & 15);
        agp[j] = A16 + (size_t)(m0 + rr) * KDIM + glog * 8;
        alp[j] = ((lf16*)As) + c * 512 + lane * 8;
    }
    const _Float16* bgp[4]; lf16* blp[4];
    #pragma unroll
    for (int j = 0; j < 4; ++j) {
        int c = j * 4 + w;
        int rr = c * 4 + rofs4;
        int glog = gs ^ (rr & 15);
        bgp[j] = B16 + (size_t)(n0 + rr) * KDIM + glog * 8;
        blp[j] = ((lf16*)Bs) + c * 512 + lane * 8;
    }

    f32x4 acc[2][4] = {};

    for (int it = 0; it < 6; ++it) {
        const int ke = it * 128;
        __syncthreads();
        #pragma unroll
        for (int j = 0; j < 8; ++j) dma16(agp[j] + ke, alp[j]);
        #pragma unroll
        for (int j = 0; j < 4; ++j) dma16(bgp[j] + ke, blp[j]);
        __syncthreads();
        #pragma unroll
        for (int s = 0; s < 4; ++s) {
            const int gq = ((s * 4 + quad) ^ mm) * 8;
            f16x8 ah[2];
            #pragma unroll
            for (int mt = 0; mt < 2; ++mt)
                ah[mt] = *(const f16x8*)&As[(w * 32 + mt * 16 + mm) * 128 + gq];
            #pragma unroll
            for (int nt = 0; nt < 4; ++nt) {
                f16x8 bh = *(const f16x8*)&Bs[(nt * 16 + mm) * 128 + gq];
                #pragma unroll
                for (int mt = 0; mt < 2; ++mt)
                    acc[mt][nt] = MFMA16(ah[mt], bh, acc[mt][nt]);
            }
        }
    }

    #pragma unroll
    for (int mt = 0; mt < 2; ++mt)
        #pragma unroll
        for (int r = 0; r < 4; ++r) {
            int row = m0 + w * 32 + mt * 16 + quad * 4 + r;
            float* cp = &C[(size_t)row * 768 + n0 + mm];
            #pragma unroll
            for (int nt = 0; nt < 4; ++nt)
                cp[nt * 16] = acc[mt][nt][r];
        }
}

// ---------------- MFMA flash attention v6: dbuf LDS, 1 barrier/chunk -------
// grid = 768 (1D); 96 consecutive logical blocks (≈ one KV plane) per XCD.
__global__ __launch_bounds__(256) void attn_mfma(const _Float16* __restrict__ q16,
                                                 const _Float16* __restrict__ k16,
                                                 const _Float16* __restrict__ vT16,
                                                 _Float16* __restrict__ aout16) {
    __shared__ __align__(16) char smem[32768 + 10240];         // 42 KB
    _Float16* k_s  = (_Float16*)smem;                          // [2][64*64] swz
    _Float16* vT_s = (_Float16*)(smem + 16384);                // [2][64*64] swz
    _Float16 (*p_s)[40] = (_Float16(*)[40])(smem + 32768);     // [128][40]
    float* ored = (float*)smem;                                // [64][64] end overlay
    float* lred = (float*)(smem + 16384);                      // [64]     end overlay

    const int lb = xcdswz(blockIdx.x, 96);                     // 768/8
    const int b = lb / 384;
    const int rrem = lb % 384;
    const int h = rrem >> 5;
    const int i0 = (rrem & 31) * 64;
    const int plane = b * 3 + (h >> 2);
    const int tid = threadIdx.x;
    const int w = tid >> 6, lane = tid & 63;
    const int m = lane & 15, quad = lane >> 4;
    const int qh = w & 1, kh = w >> 1;
    const int xm = m & 7;

    int s0 = i0 - 512;      s0 = s0 < 0 ? 0 : (s0 > 1024 ? 1024 : s0);
    int sL = i0 + 63 - 512; sL = sL < 0 ? 0 : (sL > 1024 ? 1024 : sL);
    const int nc = (sL + WIN - s0 + 63) >> 6;

    int start_q[2];
    f16x8 qf[2][2];
    #pragma unroll
    for (int qt = 0; qt < 2; ++qt) {
        int qi = i0 + qh * 32 + qt * 16 + m;
        int sq = qi - 512; sq = sq < 0 ? 0 : (sq > 1024 ? 1024 : sq);
        start_q[qt] = sq;
        const _Float16* qp = &q16[((size_t)(b * T_SEQ + qi)) * E + h * 64 + quad * 8];
        qf[qt][0] = *(const f16x8*)&qp[0];
        qf[qt][1] = *(const f16x8*)&qp[32];
    }

    f32x4 o[2][4] = {};
    float l_run[2] = {0.0f, 0.0f};

    const int rofs = lane >> 3;
    const int glog = (lane & 7) ^ rofs;
    const _Float16* kgb[2]; const _Float16* vgb[2];
    _Float16* klw[2]; _Float16* vlw[2];
    #pragma unroll
    for (int j = 0; j < 2; ++j) {
        int rr = (j * 4 + w) * 8 + rofs;
        kgb[j] = k16 + ((size_t)plane * T_SEQ + rr) * 64 + glog * 8;
        vgb[j] = vT16 + ((size_t)plane * 64 + rr) * T_SEQ + glog * 8;
        klw[j] = k_s + (j * 4 + w) * 512 + lane * 8;
        vlw[j] = vT_s + (j * 4 + w) * 512 + lane * 8;
    }

    // prologue: chunk 0 -> regs -> buf0
    f16x8 kr[2], vr[2];
    #pragma unroll
    for (int j = 0; j < 2; ++j) {
        kr[j] = *(const f16x8*)(kgb[j] + (size_t)s0 * 64);
        vr[j] = *(const f16x8*)(vgb[j] + s0);
    }
    #pragma unroll
    for (int j = 0; j < 2; ++j) {
        *(f16x8*)klw[j] = kr[j];
        *(f16x8*)vlw[j] = vr[j];
    }

    for (int ci = 0; ci < nc; ++ci) {
        const int c0 = s0 + ci * 64;
        const int sel = (ci & 1) * 4096;
        __syncthreads();                 // buf[sel] visible; prev readers done
        if (ci + 1 < nc) {               // prefetch next chunk into regs
            const int cn = c0 + 64;
            #pragma unroll
            for (int j = 0; j < 2; ++j) {
                kr[j] = *(const f16x8*)(kgb[j] + (size_t)cn * 64);
                vr[j] = *(const f16x8*)(vgb[j] + cn);
            }
        }

        f32x4 st[2][2] = {};
        #pragma unroll
        for (int s = 0; s < 2; ++s) {
            #pragma unroll
            for (int kt = 0; kt < 2; ++kt) {
                int row = kh * 32 + kt * 16 + m;
                int g = (s * 4 + quad) ^ xm;
                f16x8 a = *(const f16x8*)&k_s[sel + row * 64 + g * 8];
                #pragma unroll
                for (int qt = 0; qt < 2; ++qt)
                    st[kt][qt] = MFMA16(a, qf[qt][s], st[kt][qt]);
            }
        }

        const bool boundary = (c0 < sL) || (c0 + 63 > s0 + 1023);
        if (boundary) {
            #pragma unroll
            for (int kt = 0; kt < 2; ++kt)
                #pragma unroll
                for (int qt = 0; qt < 2; ++qt)
                    #pragma unroll
                    for (int r = 0; r < 4; ++r) {
                        int j = c0 + kh * 32 + kt * 16 + quad * 4 + r;
                        bool valid = (j >= start_q[qt]) && (j < start_q[qt] + WIN);
                        st[kt][qt][r] = valid ? st[kt][qt][r] : -INFINITY;
                    }
        }

        #pragma unroll
        for (int kt = 0; kt < 2; ++kt)
            #pragma unroll
            for (int qt = 0; qt < 2; ++qt) {
                float p0 = __expf(st[kt][qt][0]);
                float p1 = __expf(st[kt][qt][1]);
                float p2 = __expf(st[kt][qt][2]);
                float p3 = __expf(st[kt][qt][3]);
                l_run[qt] += (p0 + p1) + (p2 + p3);
                f16x4 pv = {(_Float16)p0, (_Float16)p1, (_Float16)p2, (_Float16)p3};
                *(f16x4*)&p_s[w * 32 + qt * 16 + m][kt * 16 + quad * 4] = pv;
            }

        f16x8 bp[2];
        #pragma unroll
        for (int qt = 0; qt < 2; ++qt)
            bp[qt] = *(const f16x8*)&p_s[w * 32 + qt * 16 + m][quad * 8];
        #pragma unroll
        for (int mt = 0; mt < 4; ++mt) {
            int g = (kh * 4 + quad) ^ xm;
            f16x8 a = *(const f16x8*)&vT_s[sel + (mt * 16 + m) * 64 + g * 8];
            #pragma unroll
            for (int qt = 0; qt < 2; ++qt)
                o[qt][mt] = MFMA16(a, bp[qt], o[qt][mt]);
        }

        if (ci + 1 < nc) {               // write next chunk to other buffer
            const int ns = ((ci + 1) & 1) * 4096;
            #pragma unroll
            for (int j = 0; j < 2; ++j) {
                *(f16x8*)(klw[j] + ns) = kr[j];
                *(f16x8*)(vlw[j] + ns) = vr[j];
            }
        }
    }

    float l_tot[2];
    #pragma unroll
    for (int qt = 0; qt < 2; ++qt) {
        float l = l_run[qt];
        l += __shfl_xor(l, 16);
        l += __shfl_xor(l, 32);
        l_tot[qt] = l;
    }

    __syncthreads();
    if (kh == 1) {
        #pragma unroll
        for (int qt = 0; qt < 2; ++qt) {
            #pragma unroll
            for (int mt = 0; mt < 4; ++mt) {
                int idx = ((qh * 32 + qt * 16 + m) << 6) + mt * 16 + quad * 4;
                *(float4*)&ored[idx] = *(float4*)&o[qt][mt];
            }
            if (quad == 0) lred[qh * 32 + qt * 16 + m] = l_tot[qt];
        }
    }
    __syncthreads();
    if (kh == 0) {
        #pragma unroll
        for (int qt = 0; qt < 2; ++qt) {
            float rl = 1.0f / (l_tot[qt] + lred[qh * 32 + qt * 16 + m]);
            int qi = i0 + qh * 32 + qt * 16 + m;
            _Float16* op = &aout16[((size_t)(b * T_SEQ + qi)) * E + h * 64];
            #pragma unroll
            for (int mt = 0; mt < 4; ++mt) {
                int idx = ((qh * 32 + qt * 16 + m) << 6) + mt * 16 + quad * 4;
                float4 other = *(float4*)&ored[idx];
                f16x4 hv;
                #pragma unroll
                for (int r = 0; r < 4; ++r)
                    hv[r] = (_Float16)((o[qt][mt][r] + (&other.x)[r]) * rl);
                *(f16x4*)&op[mt * 16 + quad * 4] = hv;
            }
        }
    }
}

extern "C" void kernel_launch(void* const* d_in, const int* in_sizes, int n_in,
                              void* d_out, int out_size, void* d_ws, size_t ws_size,
                              hipStream_t stream) {
    const float* hs = (const float*)d_in[0];
    const float* Wq = (const float*)d_in[1];
    const float* Wk = (const float*)d_in[2];
    const float* Wv = (const float*)d_in[3];
    const float* Wo = (const float*)d_in[4];
    float* out = (float*)d_out;

    _Float16* hs16   = (_Float16*)d_ws;             // 4096*768 f16
    _Float16* aout16 = hs16 + HS_SZ;                // 4096*768
    _Float16* q16    = aout16 + HS_SZ;              // 4096*768
    _Float16* k16    = q16 + HS_SZ;                 // 6*2048*64
    _Float16* vT16   = k16 + 6 * 2048 * 64;         // 6*64*2048
    _Float16* Wq16   = vT16 + 6 * 2048 * 64;        // 768*768
    _Float16* Wk16   = Wq16 + 768 * 768;            // 192*768
    _Float16* Wv16   = Wk16 + 192 * 768;            // 192*768
    _Float16* Wo16   = Wv16 + 192 * 768;            // 768*768
    float2*   rtab   = (float2*)(Wo16 + 768 * 768); // 2048*32 float2

    dim3 blk(256);
    prep<<<dim3((int)(HS_SZ / 8 / 256)), blk, 0, stream>>>(hs, Wq, Wk, Wv, Wo,
                                                           hs16, Wq16, Wk16, Wv16, Wo16, rtab);
    gemm_qkv<<<dim3(576), blk, 0, stream>>>(hs16, Wq16, Wk16, Wv16, rtab, q16, k16, vT16);
    attn_mfma<<<dim3(768), blk, 0, stream>>>(q16, k16, vT16, aout16);
    gemm_out<<<dim3(384), blk, 0, stream>>>(aout16, Wo16, out);
}